// Round 15
// baseline (933.093 us; speedup 1.0000x reference)
//
#include <hip/hip_runtime.h>

#define TT 256
#define BATCH 2048
#define DATA 32
#define WSLOTS 52

typedef __bf16 bf16x8 __attribute__((ext_vector_type(8)));
typedef float f32x4 __attribute__((ext_vector_type(4)));

#define MFMA(A, B, C) __builtin_amdgcn_mfma_f32_16x16x32_bf16((A), (B), (C), 0, 0, 0)

union bfp2 { unsigned u; __bf16 b[2]; };
union bfq  { uint2 u; __bf16 b[4]; };
union bfx8 { uint4 q; bf16x8 v; __bf16 b[8]; unsigned w[4]; };

// fp32 x8 (global) -> bf16x8 fragment (prologue only)
__device__ __forceinline__ bf16x8 ldw8(const float* __restrict__ p) {
    float4 a = *(const float4*)p;
    float4 b = *(const float4*)(p + 4);
    bf16x8 r;
    r[0] = (__bf16)a.x; r[1] = (__bf16)a.y; r[2] = (__bf16)a.z; r[3] = (__bf16)a.w;
    r[4] = (__bf16)b.x; r[5] = (__bf16)b.y; r[6] = (__bf16)b.z; r[7] = (__bf16)b.w;
    return r;
}

// swizzled LDS fragment read for h buffers: 256-B rows, 16-B slot XOR (row&7)
__device__ __forceinline__ bf16x8 ldx(const char* base, int row, int kbyte) {
    return *(const bf16x8*)(base + row * 256 + (kbyte ^ ((row & 7) << 4)));
}

// One 16-col output tile (this wave's 1/8 share of a 128-wide layer).
#define HID1(WF, KC, SRC, DST, BI)                                                    \
    {                                                                                 \
        bf16x8 xf[4];                                                                 \
        _Pragma("unroll") for (int kc = 0; kc < (KC); ++kc)                           \
            xf[kc] = ldx(SRC, m, kc * 64 + g * 16);                                   \
        f32x4 ac = BI;                                                                \
        _Pragma("unroll") for (int kc = 0; kc < (KC); ++kc)                           \
            ac = MFMA(WF[kc], xf[kc], ac);                                            \
        bfq p0;                                                                       \
        _Pragma("unroll") for (int j = 0; j < 4; ++j)                                 \
            p0.b[j] = (__bf16)fmaxf(ac[j], 0.0f);                                     \
        *(uint2*)((DST) + m * 256 + ((tbB2 + g * 8) ^ sw)) = p0.u;                    \
    }

// Per-wave delay lerp into registers (B-layout frags). hist rows 80-B stride:
// b128 over 16 lanes = exact 2-way banks (free, m136).
#define LERP2(TQT, O1, O2)                                                            \
    {                                                                                 \
        _Pragma("unroll") for (int dl = 0; dl < 2; ++dl) {                            \
            const float tau = dl ? 2.0f : 1.0f;                                       \
            float s = ((TQT) - tau - t0v) * ivd0;                                     \
            s = fminf(fmaxf(s, 0.0f), 255.0f);                                        \
            const int   i0 = (int)s;                                                  \
            const int   i1 = min(i0 + 1, TT - 1);                                     \
            const float w  = s - (float)i0;                                           \
            bfx8 pa, pb, pr;                                                          \
            pa.v = *(const bf16x8*)(hists + (i0 % WSLOTS) * 1280 + m * 80 + g * 16);  \
            pb.v = *(const bf16x8*)(hists + (i1 % WSLOTS) * 1280 + m * 80 + g * 16);  \
            _Pragma("unroll") for (int e = 0; e < 8; ++e) {                           \
                const float va = (float)pa.b[e];                                      \
                pr.b[e] = (__bf16)fmaf(w, (float)pb.b[e] - va, va);                   \
            }                                                                         \
            if (dl == 0) O1 = pr.v; else O2 = pr.v;                                   \
        }                                                                             \
    }

// One RK stage: 3 barriers. y/k fp32 D-layout regs, replicated in all 8 waves
// (lane (m,g): y[t2][j] = feature t2*16+4g+j of sample m). xf0 B-frag built by
// in-wave ds_bpermute (D->B lane permutation) -- no LDS buffer, no barrier.
#define DO_STAGE(USEK, CST, KP, KD, XI1, XI2, XO1, XO2, TQN, FIN, I)                  \
    {                                                                                 \
        /* SegA: yst (D-layout) -> pack -> bpermute -> xf0 ; L0 -> hA */              \
        float yst[2][4];                                                              \
        _Pragma("unroll") for (int t2 = 0; t2 < 2; ++t2)                              \
            _Pragma("unroll") for (int j = 0; j < 4; ++j)                             \
                yst[t2][j] = (USEK) ? fmaf((CST) * dt, KP[t2][j], y[t2][j])           \
                                    : y[t2][j];                                       \
        unsigned pk2[2][2];                                                           \
        _Pragma("unroll") for (int t2 = 0; t2 < 2; ++t2)                              \
            _Pragma("unroll") for (int s2 = 0; s2 < 2; ++s2) {                        \
                bfp2 pp;                                                              \
                pp.b[0] = (__bf16)yst[t2][2 * s2];                                    \
                pp.b[1] = (__bf16)yst[t2][2 * s2 + 1];                                \
                pk2[t2][s2] = pp.u;                                                   \
            }                                                                         \
        bfx8 xf0;                                                                     \
        _Pragma("unroll") for (int s2 = 0; s2 < 2; ++s2) {                            \
            int aa = __builtin_amdgcn_ds_bpermute(pa0, (int)pk2[0][s2]);              \
            int bb = __builtin_amdgcn_ds_bpermute(pa0, (int)pk2[1][s2]);              \
            int cc = __builtin_amdgcn_ds_bpermute(pa1, (int)pk2[0][s2]);              \
            int dd = __builtin_amdgcn_ds_bpermute(pa1, (int)pk2[1][s2]);              \
            xf0.w[s2]     = tsel ? (unsigned)bb : (unsigned)aa;                       \
            xf0.w[2 + s2] = tsel ? (unsigned)dd : (unsigned)cc;                       \
        }                                                                             \
        {                                                                             \
            f32x4 a0c = bias0;                                                        \
            a0c = MFMA(W0f[1], XI1, a0c);      /* lerp chunks first (regs ready) */   \
            a0c = MFMA(W0f[2], XI2, a0c);                                             \
            a0c = MFMA(W0f[0], xf0.v, a0c);                                           \
            bfq p0;                                                                   \
            _Pragma("unroll") for (int j = 0; j < 4; ++j)                             \
                p0.b[j] = (__bf16)fmaxf(a0c[j], 0.0f);                                \
            *(uint2*)(hA + m * 256 + ((tbB2 + g * 8) ^ sw)) = p0.u;                   \
        }                                                                             \
        __syncthreads();                                                              \
        HID1(W1f, 4, hA, hB, bias1)                                                   \
        __syncthreads();                                                              \
        HID1(W2f, 4, hB, hC, bias2)                                                   \
        __syncthreads();                                                              \
        {   /* SegD: lerp-next (issue first) + redundant L3 in ALL waves -> KD */     \
            LERP2(TQN, XO1, XO2)                                                      \
            bf16x8 hx[4];                                                             \
            _Pragma("unroll") for (int kc = 0; kc < 4; ++kc)                          \
                hx[kc] = ldx(hC, m, kc * 64 + g * 16);                                \
            _Pragma("unroll") for (int t2 = 0; t2 < 2; ++t2) {                        \
                f32x4 a3 = bias3D[t2];                                                \
                _Pragma("unroll") for (int kc = 0; kc < 4; ++kc)                      \
                    a3 = MFMA(W3f[t2][kc], hx[kc], a3);                               \
                KD[t2] = a3;                                                          \
            }                                                                         \
            if (FIN) {   /* RK combine (D-layout), hist/out by wave 0 */              \
                _Pragma("unroll") for (int t2 = 0; t2 < 2; ++t2)                      \
                    _Pragma("unroll") for (int j = 0; j < 4; ++j) {                   \
                        const float ks = (2.0f / 9.0f) * k1[t2][j]                    \
                                       + (1.0f / 3.0f) * k2[t2][j]                    \
                                       + (4.0f / 9.0f) * KD[t2][j];                   \
                        y[t2][j] = fmaf(dt, ks, y[t2][j]);                            \
                    }                                                                 \
                if (wv == 0) {                                                        \
                    _Pragma("unroll") for (int t2 = 0; t2 < 2; ++t2) {                \
                        bfq p; float4 v;                                              \
                        p.b[0] = (__bf16)y[t2][0]; p.b[1] = (__bf16)y[t2][1];         \
                        p.b[2] = (__bf16)y[t2][2]; p.b[3] = (__bf16)y[t2][3];         \
                        v.x = y[t2][0]; v.y = y[t2][1];                               \
                        v.z = y[t2][2]; v.w = y[t2][3];                               \
                        *(uint2*)(hists + (((I) + 1) % WSLOTS) * 1280 + m * 80        \
                                  + t2 * 32 + g * 8) = p.u;                           \
                        *(float4*)(out + (size_t)((I) + 1) * BATCH * DATA             \
                                   + (R0 + m) * DATA + t2 * 16 + g * 4) = v;          \
                    }                                                                 \
                }                                                                     \
            }                                                                         \
        }                                                                             \
    }

__global__ __launch_bounds__(512, 1) void dde_p(
    const float* __restrict__ ts, const float* __restrict__ y0,
    const float* __restrict__ W0, const float* __restrict__ b0,
    const float* __restrict__ W1, const float* __restrict__ b1,
    const float* __restrict__ W2, const float* __restrict__ b2,
    const float* __restrict__ W3, const float* __restrict__ b3,
    float* __restrict__ out)
{
    __shared__ __align__(16) char hists[WSLOTS * 1280]; // [slot][m][32bf16], 80-B rows
    __shared__ __align__(16) char hA[16 * 256];
    __shared__ __align__(16) char hB[16 * 256];
    __shared__ __align__(16) char hC[16 * 256];
    __shared__ float tsb[TT];
    // ~78 KB LDS, 1 block/CU, 8 waves = 2 per SIMD

    const int tid  = threadIdx.x;
    const int lane = tid & 63;
    const int wv   = tid >> 6;        // wave 0..7 -> one N-tile of hidden layers
    const int m    = lane & 15;       // batch row within block
    const int g    = lane >> 4;       // quad index (D rows / B k-octets)
    const int tbB2 = wv * 32;         // byte base of this wave's hidden tile
    const int sw   = (m & 7) << 4;
    const int R0   = blockIdx.x * 16;
    const int pa0  = (m + ((g & 1) << 5)) << 2;   // bpermute byte addr: lane (m, 2(g&1))
    const int pa1  = pa0 + 64;                    // lane (m, 2(g&1)+1)
    const int tsel = g >> 1;                      // tile select for D->B permute

    for (int idx = tid; idx < WSLOTS * 320; idx += 512) ((unsigned*)hists)[idx] = 0u;
    if (tid < TT) tsb[tid] = ts[tid];

    // ---- register-resident weight fragments ----
    bf16x8 W0f[3], W1f[4], W2f[4], W3f[2][4];
    {
        const int rw = wv * 16 + m;
        #pragma unroll
        for (int kc = 0; kc < 3; ++kc) W0f[kc] = ldw8(W0 + rw * 96 + kc * 32 + g * 8);
        #pragma unroll
        for (int kc = 0; kc < 4; ++kc) W1f[kc] = ldw8(W1 + rw * 128 + kc * 32 + g * 8);
        #pragma unroll
        for (int kc = 0; kc < 4; ++kc) W2f[kc] = ldw8(W2 + rw * 128 + kc * 32 + g * 8);
        #pragma unroll
        for (int t2 = 0; t2 < 2; ++t2)      // all waves: L3 is redundant
            #pragma unroll
            for (int kc = 0; kc < 4; ++kc)
                W3f[t2][kc] = ldw8(W3 + (t2 * 16 + m) * 128 + kc * 32 + g * 8);
    }
    f32x4 bias0, bias1, bias2, bias3D[2];
    bias0 = *(const f32x4*)(b0 + wv * 16 + g * 4);
    bias1 = *(const f32x4*)(b1 + wv * 16 + g * 4);
    bias2 = *(const f32x4*)(b2 + wv * 16 + g * 4);
    #pragma unroll
    for (int t2 = 0; t2 < 2; ++t2)
        bias3D[t2] = *(const f32x4*)(b3 + t2 * 16 + g * 4);  // D-layout: feat t2*16+4g+j

    __syncthreads();   // hist zero complete

    // ---- state init: y/k D-layout fp32, replicated in all waves ----
    f32x4 y[2], k1[2], k2[2], k3[2];
    #pragma unroll
    for (int t2 = 0; t2 < 2; ++t2) {
        float4 vv = *(const float4*)(y0 + (R0 + m) * DATA + t2 * 16 + g * 4);
        y[t2][0] = vv.x; y[t2][1] = vv.y; y[t2][2] = vv.z; y[t2][3] = vv.w;
        k1[t2] = f32x4{0.f, 0.f, 0.f, 0.f}; k2[t2] = k1[t2]; k3[t2] = k1[t2];
        if (wv == 0) {
            bfq p;
            p.b[0] = (__bf16)vv.x; p.b[1] = (__bf16)vv.y;
            p.b[2] = (__bf16)vv.z; p.b[3] = (__bf16)vv.w;
            *(uint2*)(hists + m * 80 + t2 * 32 + g * 8) = p.u;   // hist slot 0 = y0
            *(float4*)(out + (R0 + m) * DATA + t2 * 16 + g * 4) = vv;  // ys[0] exact
        }
    }
    if (blockIdx.x == 0 && tid == 0)
        out[(size_t)TT * BATCH * DATA] = 255.0f;   // tuple output 1: int32(T-1)
    __syncthreads();   // hist slot 0 visible

    const float t0v  = tsb[0];
    const float ivd0 = 1.0f / (tsb[1] - tsb[0]);

    // ---- prologue: lerp frags for step-0 stage-0 (tq = t0) ----
    bf16x8 xlA1, xlA2, xlB1, xlB2, xlC1, xlC2;
    LERP2(t0v, xlA1, xlA2)

    #pragma unroll 1
    for (int i = 0; i < TT - 1; ++i) {
        const float t  = tsb[i];
        const float tn = tsb[i + 1];
        const float dt = tn - t;

        DO_STAGE(0, 0.0f,  k1, k1, xlA1, xlA2, xlB1, xlB2, fmaf(0.5f, dt, t), 0, i)
        DO_STAGE(1, 0.5f,  k1, k2, xlB1, xlB2, xlC1, xlC2, fmaf(0.75f, dt, t), 0, i)
        DO_STAGE(2, 0.75f, k2, k3, xlC1, xlC2, xlA1, xlA2, tn, 1, i)

        // Hazards: hA written SegA, read SegB; next write >= 2 barriers after read.
        // hB: SegB->SegC, same. hC: written SegC, read SegD; next write (SegC')
        // is >= 2 barriers (b1', b2') after the read. hist slot i+1 written in
        // SegD (wave 0) vs lerp reads of slots <= i-24: disjoint addresses; its
        // first reader is >= 24 steps (72+ barriers) later. bpermute is in-wave.
    }
}

extern "C" void kernel_launch(void* const* d_in, const int* in_sizes, int n_in,
                              void* d_out, int out_size, void* d_ws, size_t ws_size,
                              hipStream_t stream) {
    const float* ts = (const float*)d_in[0];
    const float* y0 = (const float*)d_in[1];
    const float* W0 = (const float*)d_in[2];
    const float* b0 = (const float*)d_in[3];
    const float* W1 = (const float*)d_in[4];
    const float* b1 = (const float*)d_in[5];
    const float* W2 = (const float*)d_in[6];
    const float* b2 = (const float*)d_in[7];
    const float* W3 = (const float*)d_in[8];
    const float* b3 = (const float*)d_in[9];

    dde_p<<<dim3(BATCH / 16), dim3(512), 0, stream>>>(
        ts, y0, W0, b0, W1, b1, W2, b2, W3, b3, (float*)d_out);
}

// Round 16
// 846.977 us; speedup vs baseline: 1.1017x; 1.1017x over previous
//
#include <hip/hip_runtime.h>

#define TT 256
#define BATCH 2048
#define DATA 32
#define WSLOTS 52

typedef __bf16 bf16x8 __attribute__((ext_vector_type(8)));
typedef float f32x4 __attribute__((ext_vector_type(4)));

#define MFMA(A, B, C) __builtin_amdgcn_mfma_f32_16x16x32_bf16((A), (B), (C), 0, 0, 0)

union bfp2 { unsigned u; __bf16 b[2]; };
union bfq  { uint2 u; __bf16 b[4]; };
union bfx8 { uint4 q; bf16x8 v; __bf16 b[8]; unsigned w[4]; };

// fp32 x8 (global) -> bf16x8 fragment (prologue only)
__device__ __forceinline__ bf16x8 ldw8(const float* __restrict__ p) {
    float4 a = *(const float4*)p;
    float4 b = *(const float4*)(p + 4);
    bf16x8 r;
    r[0] = (__bf16)a.x; r[1] = (__bf16)a.y; r[2] = (__bf16)a.z; r[3] = (__bf16)a.w;
    r[4] = (__bf16)b.x; r[5] = (__bf16)b.y; r[6] = (__bf16)b.z; r[7] = (__bf16)b.w;
    return r;
}

// swizzled LDS fragment read for h buffers: 256-B rows, 16-B slot XOR (row&7)
__device__ __forceinline__ bf16x8 ldx(const char* base, int row, int kbyte) {
    return *(const bf16x8*)(base + row * 256 + (kbyte ^ ((row & 7) << 4)));
}

// Two 16-col output tiles (this wave's 2/8 share of a 128-wide layer). [R10]
#define HID2(WF, KC, SRC, DST, BI0, BI1)                                              \
    {                                                                                 \
        bf16x8 xf[4];                                                                 \
        _Pragma("unroll") for (int kc = 0; kc < (KC); ++kc)                           \
            xf[kc] = ldx(SRC, m, kc * 64 + g * 16);                                   \
        f32x4 a0 = BI0, a1 = BI1;                                                     \
        _Pragma("unroll") for (int kc = 0; kc < (KC); ++kc) {                         \
            a0 = MFMA(WF[0][kc], xf[kc], a0);                                         \
            a1 = MFMA(WF[1][kc], xf[kc], a1);                                         \
        }                                                                             \
        bfq p0, p1;                                                                   \
        _Pragma("unroll") for (int j = 0; j < 4; ++j) {                               \
            p0.b[j] = (__bf16)fmaxf(a0[j], 0.0f);                                     \
            p1.b[j] = (__bf16)fmaxf(a1[j], 0.0f);                                     \
        }                                                                             \
        char* dr = (DST) + m * 256;                                                   \
        *(uint2*)(dr + ((tbB + g * 8) ^ sw)) = p0.u;                                  \
        *(uint2*)(dr + ((tbB + 32 + g * 8) ^ sw)) = p1.u;                             \
    }

// Per-wave delay lerp into registers (B-layout frags). hist rows 80-B stride:
// b128 over 16 lanes = exact 2-way banks (free, m136). [R15-verified]
#define LERP2(TQT, O1, O2)                                                            \
    {                                                                                 \
        _Pragma("unroll") for (int dl = 0; dl < 2; ++dl) {                            \
            const float tau = dl ? 2.0f : 1.0f;                                       \
            float s = ((TQT) - tau - t0v) * ivd0;                                     \
            s = fminf(fmaxf(s, 0.0f), 255.0f);                                        \
            const int   i0 = (int)s;                                                  \
            const int   i1 = min(i0 + 1, TT - 1);                                     \
            const float w  = s - (float)i0;                                           \
            bfx8 pa, pb, pr;                                                          \
            pa.v = *(const bf16x8*)(hists + (i0 % WSLOTS) * 1280 + m * 80 + g * 16);  \
            pb.v = *(const bf16x8*)(hists + (i1 % WSLOTS) * 1280 + m * 80 + g * 16);  \
            _Pragma("unroll") for (int e = 0; e < 8; ++e) {                           \
                const float va = (float)pa.b[e];                                      \
                pr.b[e] = (__bf16)fmaf(w, (float)pb.b[e] - va, va);                   \
            }                                                                         \
            if (dl == 0) O1 = pr.v; else O2 = pr.v;                                   \
        }                                                                             \
    }

// One RK stage: 3 barriers, 4 waves (1/SIMD). y/k fp32 D-layout regs replicated
// in all waves; xf0 B-frag via in-wave ds_bpermute [R15-verified]; lerp frags in
// registers chained stage-to-stage; L3 redundant in all waves (idle matrix pipe).
#define DO_STAGE(USEK, CST, KP, KD, XI1, XI2, XO1, XO2, TQN, FIN, I)                  \
    {                                                                                 \
        /* SegA: yst (D-layout) -> pack -> bpermute -> xf0 ; full L0 -> hA */         \
        float yst[2][4];                                                              \
        _Pragma("unroll") for (int t2 = 0; t2 < 2; ++t2)                              \
            _Pragma("unroll") for (int j = 0; j < 4; ++j)                             \
                yst[t2][j] = (USEK) ? fmaf((CST) * dt, KP[t2][j], y[t2][j])           \
                                    : y[t2][j];                                       \
        unsigned pk2[2][2];                                                           \
        _Pragma("unroll") for (int t2 = 0; t2 < 2; ++t2)                              \
            _Pragma("unroll") for (int s2 = 0; s2 < 2; ++s2) {                        \
                bfp2 pp;                                                              \
                pp.b[0] = (__bf16)yst[t2][2 * s2];                                    \
                pp.b[1] = (__bf16)yst[t2][2 * s2 + 1];                                \
                pk2[t2][s2] = pp.u;                                                   \
            }                                                                         \
        bfx8 xf0;                                                                     \
        _Pragma("unroll") for (int s2 = 0; s2 < 2; ++s2) {                            \
            int aa = __builtin_amdgcn_ds_bpermute(pa0, (int)pk2[0][s2]);              \
            int bb = __builtin_amdgcn_ds_bpermute(pa0, (int)pk2[1][s2]);              \
            int cc = __builtin_amdgcn_ds_bpermute(pa1, (int)pk2[0][s2]);              \
            int dd = __builtin_amdgcn_ds_bpermute(pa1, (int)pk2[1][s2]);              \
            xf0.w[s2]     = tsel ? (unsigned)bb : (unsigned)aa;                       \
            xf0.w[2 + s2] = tsel ? (unsigned)dd : (unsigned)cc;                       \
        }                                                                             \
        {                                                                             \
            f32x4 a0 = bias0[0], a1 = bias0[1];                                       \
            a0 = MFMA(W0f[0][1], XI1, a0);   a1 = MFMA(W0f[1][1], XI1, a1);           \
            a0 = MFMA(W0f[0][2], XI2, a0);   a1 = MFMA(W0f[1][2], XI2, a1);           \
            a0 = MFMA(W0f[0][0], xf0.v, a0); a1 = MFMA(W0f[1][0], xf0.v, a1);         \
            bfq p0, p1;                                                               \
            _Pragma("unroll") for (int j = 0; j < 4; ++j) {                           \
                p0.b[j] = (__bf16)fmaxf(a0[j], 0.0f);                                 \
                p1.b[j] = (__bf16)fmaxf(a1[j], 0.0f);                                 \
            }                                                                         \
            char* dr = hA + m * 256;                                                  \
            *(uint2*)(dr + ((tbB + g * 8) ^ sw)) = p0.u;                              \
            *(uint2*)(dr + ((tbB + 32 + g * 8) ^ sw)) = p1.u;                         \
        }                                                                             \
        __syncthreads();                                                              \
        HID2(W1f, 4, hA, hB, bias1[0], bias1[1])                                      \
        __syncthreads();                                                              \
        HID2(W2f, 4, hB, hC, bias2[0], bias2[1])                                      \
        __syncthreads();                                                              \
        {   /* SegD: lerp-next (regs) + redundant full L3 (idle pipe) -> KD */        \
            LERP2(TQN, XO1, XO2)                                                      \
            bf16x8 hx[4];                                                             \
            _Pragma("unroll") for (int kc = 0; kc < 4; ++kc)                          \
                hx[kc] = ldx(hC, m, kc * 64 + g * 16);                                \
            _Pragma("unroll") for (int t2 = 0; t2 < 2; ++t2) {                        \
                f32x4 a3 = bias3D[t2];                                                \
                _Pragma("unroll") for (int kc = 0; kc < 4; ++kc)                      \
                    a3 = MFMA(W3f[t2][kc], hx[kc], a3);                               \
                KD[t2] = a3;                                                          \
            }                                                                         \
            if (FIN) {   /* RK combine (D-layout, replicated); wave 0 stores */       \
                _Pragma("unroll") for (int t2 = 0; t2 < 2; ++t2)                      \
                    _Pragma("unroll") for (int j = 0; j < 4; ++j) {                   \
                        const float ks = (2.0f / 9.0f) * k1[t2][j]                    \
                                       + (1.0f / 3.0f) * k2[t2][j]                    \
                                       + (4.0f / 9.0f) * KD[t2][j];                   \
                        y[t2][j] = fmaf(dt, ks, y[t2][j]);                            \
                    }                                                                 \
                if (wv == 0) {                                                        \
                    _Pragma("unroll") for (int t2 = 0; t2 < 2; ++t2) {                \
                        bfq p; float4 v;                                              \
                        p.b[0] = (__bf16)y[t2][0]; p.b[1] = (__bf16)y[t2][1];         \
                        p.b[2] = (__bf16)y[t2][2]; p.b[3] = (__bf16)y[t2][3];         \
                        v.x = y[t2][0]; v.y = y[t2][1];                               \
                        v.z = y[t2][2]; v.w = y[t2][3];                               \
                        *(uint2*)(hists + (((I) + 1) % WSLOTS) * 1280 + m * 80        \
                                  + t2 * 32 + g * 8) = p.u;                           \
                        *(float4*)(out + (size_t)((I) + 1) * BATCH * DATA             \
                                   + (R0 + m) * DATA + t2 * 16 + g * 4) = v;          \
                    }                                                                 \
                }                                                                     \
            }                                                                         \
        }                                                                             \
    }

__global__ __launch_bounds__(256, 1) void dde_3x(
    const float* __restrict__ ts, const float* __restrict__ y0,
    const float* __restrict__ W0, const float* __restrict__ b0,
    const float* __restrict__ W1, const float* __restrict__ b1,
    const float* __restrict__ W2, const float* __restrict__ b2,
    const float* __restrict__ W3, const float* __restrict__ b3,
    float* __restrict__ out)
{
    __shared__ __align__(16) char hists[WSLOTS * 1280]; // [slot][m][32bf16], 80-B rows
    __shared__ __align__(16) char hA[16 * 256];
    __shared__ __align__(16) char hB[16 * 256];
    __shared__ __align__(16) char hC[16 * 256];
    __shared__ float tsb[TT];
    // ~80 KB LDS, 4 waves = 1 per SIMD

    const int tid  = threadIdx.x;
    const int lane = tid & 63;
    const int wv   = tid >> 6;        // wave 0..3 -> two N-tiles of hidden layers
    const int m    = lane & 15;       // batch row within block
    const int g    = lane >> 4;       // quad index (D rows / B k-octets)
    const int tbB  = wv * 64;         // byte base of this wave's first hidden tile
    const int sw   = (m & 7) << 4;
    const int R0   = blockIdx.x * 16;
    const int pa0  = (m + ((g & 1) << 5)) << 2;   // bpermute: lane (m, 2(g&1))
    const int pa1  = pa0 + 64;                    // lane (m, 2(g&1)+1)
    const int tsel = g >> 1;                      // tile select for D->B permute

    for (int idx = tid; idx < WSLOTS * 320; idx += 256) ((unsigned*)hists)[idx] = 0u;
    if (tid < TT) tsb[tid] = ts[tid];

    // ---- register-resident weight fragments ----
    bf16x8 W0f[2][3], W1f[2][4], W2f[2][4], W3f[2][4];
    #pragma unroll
    for (int ti = 0; ti < 2; ++ti) {
        const int rw = (wv * 2 + ti) * 16 + m;
        #pragma unroll
        for (int kc = 0; kc < 3; ++kc) W0f[ti][kc] = ldw8(W0 + rw * 96 + kc * 32 + g * 8);
        #pragma unroll
        for (int kc = 0; kc < 4; ++kc) W1f[ti][kc] = ldw8(W1 + rw * 128 + kc * 32 + g * 8);
        #pragma unroll
        for (int kc = 0; kc < 4; ++kc) W2f[ti][kc] = ldw8(W2 + rw * 128 + kc * 32 + g * 8);
        #pragma unroll
        for (int kc = 0; kc < 4; ++kc)              // full W3 in every wave
            W3f[ti][kc] = ldw8(W3 + (ti * 16 + m) * 128 + kc * 32 + g * 8);
    }
    f32x4 bias0[2], bias1[2], bias2[2], bias3D[2];
    #pragma unroll
    for (int ti = 0; ti < 2; ++ti) {
        bias0[ti] = *(const f32x4*)(b0 + (wv * 2 + ti) * 16 + g * 4);
        bias1[ti] = *(const f32x4*)(b1 + (wv * 2 + ti) * 16 + g * 4);
        bias2[ti] = *(const f32x4*)(b2 + (wv * 2 + ti) * 16 + g * 4);
        bias3D[ti] = *(const f32x4*)(b3 + ti * 16 + g * 4);   // D-layout
    }

    __syncthreads();   // hist zero complete

    // ---- state init: y/k D-layout fp32, replicated in all 4 waves ----
    f32x4 y[2], k1[2], k2[2], k3[2];
    #pragma unroll
    for (int t2 = 0; t2 < 2; ++t2) {
        float4 vv = *(const float4*)(y0 + (R0 + m) * DATA + t2 * 16 + g * 4);
        y[t2][0] = vv.x; y[t2][1] = vv.y; y[t2][2] = vv.z; y[t2][3] = vv.w;
        k1[t2] = f32x4{0.f, 0.f, 0.f, 0.f}; k2[t2] = k1[t2]; k3[t2] = k1[t2];
        if (wv == 0) {
            bfq p;
            p.b[0] = (__bf16)vv.x; p.b[1] = (__bf16)vv.y;
            p.b[2] = (__bf16)vv.z; p.b[3] = (__bf16)vv.w;
            *(uint2*)(hists + m * 80 + t2 * 32 + g * 8) = p.u;   // hist slot 0 = y0
            *(float4*)(out + (R0 + m) * DATA + t2 * 16 + g * 4) = vv;  // ys[0] exact
        }
    }
    if (blockIdx.x == 0 && tid == 0)
        out[(size_t)TT * BATCH * DATA] = 255.0f;   // tuple output 1: int32(T-1)
    __syncthreads();   // hist slot 0 visible

    const float t0v  = tsb[0];
    const float ivd0 = 1.0f / (tsb[1] - tsb[0]);

    // ---- prologue: lerp frags for step-0 stage-0 (tq = t0) ----
    bf16x8 xlA1, xlA2, xlB1, xlB2, xlC1, xlC2;
    LERP2(t0v, xlA1, xlA2)

    #pragma unroll 1
    for (int i = 0; i < TT - 1; ++i) {
        const float t  = tsb[i];
        const float tn = tsb[i + 1];
        const float dt = tn - t;

        DO_STAGE(0, 0.0f,  k1, k1, xlA1, xlA2, xlB1, xlB2, fmaf(0.5f, dt, t), 0, i)
        DO_STAGE(1, 0.5f,  k1, k2, xlB1, xlB2, xlC1, xlC2, fmaf(0.75f, dt, t), 0, i)
        DO_STAGE(2, 0.75f, k2, k3, xlC1, xlC2, xlA1, xlA2, tn, 1, i)

        // Hazards: hA written SegA(s), read SegB(s); next write SegA(s+1) is
        // >=2 barriers (b2,b3) after the read. hB likewise. hC written SegC
        // (pre-b3), read SegD (post-b3); next write SegC(s+1) is >=2 barriers
        // (b1',b2') after the read. hist slot i+1 written SegD (wave 0) vs
        // LERP2 reads of slots <= i-24: disjoint; first reader >=24 steps
        // (>=72 barriers) later. bpermute + lerp frags are in-wave registers.
    }
}

extern "C" void kernel_launch(void* const* d_in, const int* in_sizes, int n_in,
                              void* d_out, int out_size, void* d_ws, size_t ws_size,
                              hipStream_t stream) {
    const float* ts = (const float*)d_in[0];
    const float* y0 = (const float*)d_in[1];
    const float* W0 = (const float*)d_in[2];
    const float* b0 = (const float*)d_in[3];
    const float* W1 = (const float*)d_in[4];
    const float* b1 = (const float*)d_in[5];
    const float* W2 = (const float*)d_in[6];
    const float* b2 = (const float*)d_in[7];
    const float* W3 = (const float*)d_in[8];
    const float* b3 = (const float*)d_in[9];

    dde_3x<<<dim3(BATCH / 16), dim3(256), 0, stream>>>(
        ts, y0, W0, b0, W1, b1, W2, b2, W3, b3, (float*)d_out);
}

// Round 17
// 706.797 us; speedup vs baseline: 1.3202x; 1.1983x over previous
//
#include <hip/hip_runtime.h>

#define TT 256
#define BATCH 2048
#define DATA 32
#define WSLOTS 52

typedef __bf16 bf16x8 __attribute__((ext_vector_type(8)));
typedef float f32x4 __attribute__((ext_vector_type(4)));

#define MFMA(A, B, C) __builtin_amdgcn_mfma_f32_16x16x32_bf16((A), (B), (C), 0, 0, 0)

union bfp2 { uint2 u; __bf16 b[4]; };
union bfp4 { uint4 q; bf16x8 v; __bf16 b[8]; };

// fp32 x8 (global) -> bf16x8 fragment (prologue only)
__device__ __forceinline__ bf16x8 ldw8(const float* __restrict__ p) {
    float4 a = *(const float4*)p;
    float4 b = *(const float4*)(p + 4);
    bf16x8 r;
    r[0] = (__bf16)a.x; r[1] = (__bf16)a.y; r[2] = (__bf16)a.z; r[3] = (__bf16)a.w;
    r[4] = (__bf16)b.x; r[5] = (__bf16)b.y; r[6] = (__bf16)b.z; r[7] = (__bf16)b.w;
    return r;
}

// swizzled LDS fragment read for hA/hB: 256-B rows, 16-B slot XOR (row&7)
__device__ __forceinline__ bf16x8 ldx(const char* base, int row, int kbyte) {
    return *(const bf16x8*)(base + row * 256 + (kbyte ^ ((row & 7) << 4)));
}

// One 16-col output tile (this wave's 1/8 share of a 128-wide layer).
// Chain split 2+2 (or 2+1) + setprio(1) around the MFMA cluster (T5).
#define HID1(WF, KC, SRC, DST, BI)                                                    \
    {                                                                                 \
        bf16x8 xf[4];                                                                 \
        _Pragma("unroll") for (int kc = 0; kc < (KC); ++kc)                           \
            xf[kc] = ldx(SRC, m, kc * 64 + g * 16);                                   \
        f32x4 a0 = BI, c0 = {0.f, 0.f, 0.f, 0.f};                                     \
        __builtin_amdgcn_s_setprio(1);                                                \
        _Pragma("unroll") for (int kc = 0; kc < (KC); ++kc) {                         \
            if (kc < 2) a0 = MFMA(WF[kc], xf[kc], a0);                                \
            else        c0 = MFMA(WF[kc], xf[kc], c0);                                \
        }                                                                             \
        __builtin_amdgcn_s_setprio(0);                                                \
        a0 = a0 + c0;                                                                 \
        bfp2 p0;                                                                      \
        _Pragma("unroll") for (int j = 0; j < 4; ++j)                                 \
            p0.b[j] = (__bf16)fmaxf(a0[j], 0.0f);                                     \
        *(uint2*)((DST) + m * 256 + ((tbB2 + g * 8) ^ sw)) = p0.u;                    \
    }

// waves 2/3 (dl = wv-2): lerp columns for time TQT -> XDST dl-region.
// hist/xb rows are 80-B stride: b128 over 16 lanes = exact 2-way banks (free).
#define PRELERP(TQT, XDST)                                                            \
    {                                                                                 \
        const int   dl  = wv - 2;                                                     \
        const float tau = dl ? 2.0f : 1.0f;                                           \
        float s = ((TQT) - tau - t0v) * ivd0;                                         \
        s = fminf(fmaxf(s, 0.0f), 255.0f);                                            \
        const int   i0 = (int)s;                                                      \
        const int   i1 = min(i0 + 1, TT - 1);                                         \
        const float w  = s - (float)i0;                                               \
        bfp4 pa, pb, pr;                                                              \
        pa.v = *(const bf16x8*)(hists + (i0 % WSLOTS) * 1280 + m * 80 + g * 16);      \
        pb.v = *(const bf16x8*)(hists + (i1 % WSLOTS) * 1280 + m * 80 + g * 16);      \
        _Pragma("unroll") for (int e = 0; e < 8; ++e) {                               \
            const float va = (float)pa.b[e];                                          \
            pr.b[e] = (__bf16)fmaf(w, (float)pb.b[e] - va, va);                       \
        }                                                                             \
        *(bf16x8*)((XDST) + dl * 1280 + m * 80 + g * 16) = pr.v;                      \
    }

// One RK stage: 4 segments, 4 barriers; 8 waves (2/SIMD). [R14 base]
#define DO_STAGE(USEK, CST, KP, KD, XSRC, XDST, TQT)                                  \
    {                                                                                 \
        /* SegA: L0 in one shot; xf0 packed from registers */                         \
        bfp4 xf0;                                                                     \
        _Pragma("unroll") for (int e = 0; e < 8; ++e)                                 \
            xf0.b[e] = (__bf16)((USEK) ? fmaf((CST) * dt, KP[e], y[e]) : y[e]);       \
        bf16x8 xl1 = *(const bf16x8*)((XSRC) + m * 80 + g * 16);                      \
        bf16x8 xl2 = *(const bf16x8*)((XSRC) + 1280 + m * 80 + g * 16);               \
        f32x4 a0 = bias0, c0 = {0.f, 0.f, 0.f, 0.f};                                  \
        __builtin_amdgcn_s_setprio(1);                                                \
        a0 = MFMA(W0f[1], xl1, a0);                                                   \
        c0 = MFMA(W0f[2], xl2, c0);                                                   \
        a0 = MFMA(W0f[0], xf0.v, a0);                                                 \
        __builtin_amdgcn_s_setprio(0);                                                \
        a0 = a0 + c0;                                                                 \
        bfp2 p0;                                                                      \
        _Pragma("unroll") for (int j = 0; j < 4; ++j)                                 \
            p0.b[j] = (__bf16)fmaxf(a0[j], 0.0f);                                     \
        *(uint2*)(hA + m * 256 + ((tbB2 + g * 8) ^ sw)) = p0.u;                       \
        __syncthreads();                                                              \
        HID1(W1f, 4, hA, hB, bias1)                                                   \
        __syncthreads();                                                              \
        HID1(W2f, 4, hB, hA, bias2)                                                   \
        __syncthreads();                                                              \
        if (wv < 2) {   /* L3 -> kbuf (D-layout, swizzled slots) */                   \
            bf16x8 xf[4];                                                             \
            _Pragma("unroll") for (int kc = 0; kc < 4; ++kc)                          \
                xf[kc] = ldx(hA, m, kc * 64 + g * 16);                                \
            f32x4 a3 = bias3, c3 = {0.f, 0.f, 0.f, 0.f};                              \
            __builtin_amdgcn_s_setprio(1);                                            \
            a3 = MFMA(W3f[0], xf[0], a3);                                             \
            c3 = MFMA(W3f[2], xf[2], c3);                                             \
            a3 = MFMA(W3f[1], xf[1], a3);                                             \
            c3 = MFMA(W3f[3], xf[3], c3);                                             \
            __builtin_amdgcn_s_setprio(0);                                            \
            a3 = a3 + c3;                                                             \
            *(f32x4*)(kbuf + m * 128 + (((wv * 4 + g) ^ (m & 7)) << 4)) = a3;         \
        } else if (wv < 4) {                                                          \
            PRELERP(TQT, XDST)                                                        \
        }                                                                             \
        __syncthreads();                                                              \
        {   /* k broadcast: all waves -> B-layout registers */                        \
            f32x4 q0 = *(const f32x4*)(kbuf + m * 128 + (((2 * g) ^ (m & 7)) << 4));  \
            f32x4 q1 = *(const f32x4*)(kbuf + m * 128 + (((2 * g + 1) ^ (m & 7)) << 4)); \
            _Pragma("unroll") for (int j = 0; j < 4; ++j) {                           \
                KD[j] = q0[j]; KD[4 + j] = q1[j];                                     \
            }                                                                         \
        }                                                                             \
    }

__global__ __launch_bounds__(512, 1) void dde_8s(
    const float* __restrict__ ts, const float* __restrict__ y0,
    const float* __restrict__ W0, const float* __restrict__ b0,
    const float* __restrict__ W1, const float* __restrict__ b1,
    const float* __restrict__ W2, const float* __restrict__ b2,
    const float* __restrict__ W3, const float* __restrict__ b3,
    float* __restrict__ out)
{
    __shared__ __align__(16) char hists[WSLOTS * 1280]; // [slot][m][32bf16], 80-B rows
    __shared__ __align__(16) char xb0[2 * 1280];        // [dl][m][32bf16] lerp buffers
    __shared__ __align__(16) char xb1[2 * 1280];
    __shared__ __align__(16) char xb2[2 * 1280];
    __shared__ __align__(16) char hA[16 * 256];
    __shared__ __align__(16) char hB[16 * 256];
    __shared__ __align__(16) char kbuf[16 * 128];       // k D-layout f32, swizzled
    __shared__ float tsb[TT];
    // ~85 KB LDS, 1 block/CU, 8 waves = 2 per SIMD

    const int tid  = threadIdx.x;
    const int lane = tid & 63;
    const int wv   = tid >> 6;        // wave 0..7 -> one N-tile of hidden layers
    const int m    = lane & 15;       // batch row within block
    const int g    = lane >> 4;       // feature-octet index
    const int tbB2 = wv * 32;         // byte base of this wave's hidden tile
    const int sw   = (m & 7) << 4;
    const int R0   = blockIdx.x * 16;

    for (int idx = tid; idx < WSLOTS * 320; idx += 512) ((unsigned*)hists)[idx] = 0u;
    if (tid < TT) tsb[tid] = ts[tid];

    // ---- register-resident weight fragments: 15 frags = 60 VGPR ----
    bf16x8 W0f[3], W1f[4], W2f[4], W3f[4];
    {
        const int rw = wv * 16 + m;
        #pragma unroll
        for (int kc = 0; kc < 3; ++kc) W0f[kc] = ldw8(W0 + rw * 96 + kc * 32 + g * 8);
        #pragma unroll
        for (int kc = 0; kc < 4; ++kc) W1f[kc] = ldw8(W1 + rw * 128 + kc * 32 + g * 8);
        #pragma unroll
        for (int kc = 0; kc < 4; ++kc) W2f[kc] = ldw8(W2 + rw * 128 + kc * 32 + g * 8);
        const int rw3 = (wv & 1) * 16 + m;   // only waves 0/1 use W3f
        #pragma unroll
        for (int kc = 0; kc < 4; ++kc) W3f[kc] = ldw8(W3 + rw3 * 128 + kc * 32 + g * 8);
    }
    f32x4 bias0, bias1, bias2, bias3;
    bias0 = *(const f32x4*)(b0 + wv * 16 + g * 4);
    bias1 = *(const f32x4*)(b1 + wv * 16 + g * 4);
    bias2 = *(const f32x4*)(b2 + wv * 16 + g * 4);
    bias3 = *(const f32x4*)(b3 + (wv & 1) * 16 + g * 4);

    __syncthreads();   // hist zero complete

    // ---- state init: y/k replicated in ALL waves, B-layout fp32 ----
    float y[8], k1[8], k2[8], k3[8];
    {
        float4 v0 = *(const float4*)(y0 + (R0 + m) * DATA + g * 8);
        float4 v1 = *(const float4*)(y0 + (R0 + m) * DATA + g * 8 + 4);
        y[0] = v0.x; y[1] = v0.y; y[2] = v0.z; y[3] = v0.w;
        y[4] = v1.x; y[5] = v1.y; y[6] = v1.z; y[7] = v1.w;
        #pragma unroll
        for (int e = 0; e < 8; ++e) { k1[e] = 0.0f; k2[e] = 0.0f; k3[e] = 0.0f; }
        if (wv == 0) {
            bfp4 p;
            #pragma unroll
            for (int e = 0; e < 8; ++e) p.b[e] = (__bf16)y[e];
            *(bf16x8*)(hists + m * 80 + g * 16) = p.v;        // hist slot 0 = y0
            *(float4*)(out + (R0 + m) * DATA + g * 8) = v0;   // ys[0] = y0 exact
            *(float4*)(out + (R0 + m) * DATA + g * 8 + 4) = v1;
        }
    }
    if (blockIdx.x == 0 && tid == 0)
        out[(size_t)TT * BATCH * DATA] = 255.0f;   // tuple output 1: int32(T-1)
    __syncthreads();   // hist slot 0 visible

    const float t0v  = tsb[0];
    const float ivd0 = 1.0f / (tsb[1] - tsb[0]);

    // ---- prologue: fill all three stage lerp buffers for step 0 ----
    if (wv >= 2 && wv < 4) {
        const float dt0 = tsb[1] - tsb[0];
        PRELERP(t0v, xb0)
        PRELERP(fmaf(0.5f, dt0, t0v), xb1)
        PRELERP(fmaf(0.75f, dt0, t0v), xb2)
    }
    __syncthreads();

    #pragma unroll 1
    for (int i = 0; i < TT - 1; ++i) {
        const float t   = tsb[i];
        const float tn  = tsb[i + 1];
        const float dt  = tn - t;
        const float tnn = tsb[min(i + 2, TT - 1)];
        const float dtn = tnn - tn;          // 0 junk on final iteration (unused)

        DO_STAGE(0, 0.0f,  k1, k1, xb0, xb2, fmaf(0.75f, dt, t))
        DO_STAGE(1, 0.5f,  k1, k2, xb1, xb0, tn)
        DO_STAGE(2, 0.75f, k2, k3, xb2, xb1, fmaf(0.5f, dtn, tn))

        {   // RK combine, replicated; hist/out stores by wave 0 (fire-and-forget)
            #pragma unroll
            for (int e = 0; e < 8; ++e) {
                const float ks = (2.0f / 9.0f) * k1[e] + (1.0f / 3.0f) * k2[e]
                               + (4.0f / 9.0f) * k3[e];
                y[e] = fmaf(dt, ks, y[e]);
            }
            if (wv == 0) {
                bfp4 p;
                #pragma unroll
                for (int e = 0; e < 8; ++e) p.b[e] = (__bf16)y[e];
                *(bf16x8*)(hists + ((i + 1) % WSLOTS) * 1280 + m * 80 + g * 16) = p.v;
                float4 o0, o1;
                o0.x = y[0]; o0.y = y[1]; o0.z = y[2]; o0.w = y[3];
                o1.x = y[4]; o1.y = y[5]; o1.z = y[6]; o1.w = y[7];
                float* op = out + (size_t)(i + 1) * BATCH * DATA + (R0 + m) * DATA + g * 8;
                *(float4*)op = o0;
                *(float4*)(op + 4) = o1;
            }
        }
        // Hazards (R14-identical): xb written SegD(s) -> read SegA(s+2): >=5
        // barriers; WAR >=7. kbuf: write SegD, b4, read; next write >=3 barriers
        // after read. hist slot i+1 written post-b4, first PRELERP read >=24
        // steps later. hA: L3-read (SegD) vs next L0-write (SegA): fenced by b4.
    }
}

extern "C" void kernel_launch(void* const* d_in, const int* in_sizes, int n_in,
                              void* d_out, int out_size, void* d_ws, size_t ws_size,
                              hipStream_t stream) {
    const float* ts = (const float*)d_in[0];
    const float* y0 = (const float*)d_in[1];
    const float* W0 = (const float*)d_in[2];
    const float* b0 = (const float*)d_in[3];
    const float* W1 = (const float*)d_in[4];
    const float* b1 = (const float*)d_in[5];
    const float* W2 = (const float*)d_in[6];
    const float* b2 = (const float*)d_in[7];
    const float* W3 = (const float*)d_in[8];
    const float* b3 = (const float*)d_in[9];

    dde_8s<<<dim3(BATCH / 16), dim3(512), 0, stream>>>(
        ts, y0, W0, b0, W1, b1, W2, b2, W3, b3, (float*)d_out);
}